// Round 1
// baseline (1140.940 us; speedup 1.0000x reference)
//
#include <hip/hip_runtime.h>
#include <math.h>

#define SIG_L 128000
#define NBATCH 64
#define NROWS 257      // fft output rows (per re/im)
#define HOP 128
#define NUMF 999       // frames = (128000+256-512)/128+1
#define NFRM 30
#define NWIN 969       // NUMF - NFRM
#define TILE_T 16
#define NTILES 63      // ceil(999/16)
#define BETA_F 6.623413251903491f  // 1 + 10^(15/20)

// ---------- K0: scan octmat for band ranges + max used bin ----------
__global__ void k_scan(const float* __restrict__ oct, int NB, int* __restrict__ hdr) {
    __shared__ int smin[16], smax[16];
    int tid = threadIdx.x;
    if (tid < NB) { smin[tid] = 0x7fffffff; smax[tid] = -1; }
    __syncthreads();
    for (int idx = tid; idx < NB * NROWS; idx += blockDim.x) {
        int k = idx / NROWS, f = idx % NROWS;
        if (oct[idx] != 0.0f) { atomicMin(&smin[k], f); atomicMax(&smax[k], f); }
    }
    __syncthreads();
    if (tid == 0) {
        int fm = 1;
        for (int k = 0; k < NB; ++k) fm = max(fm, smax[k] + 1);
        hdr[0] = fm;
    }
    if (tid < NB) {
        hdr[1 + tid]      = (smin[tid] == 0x7fffffff) ? 0 : smin[tid];
        hdr[1 + 16 + tid] = smax[tid] + 1;   // exclusive end
    }
}

// ---------- K0b: transpose used fftmat cols (128..383) to [j][row] ----------
__global__ void k_tr(const float* __restrict__ fftmat, float* __restrict__ fmatT) {
    int r = blockIdx.x;        // 0..513
    int j = threadIdx.x;       // 0..255
    fmatT[j * 514 + r] = fftmat[r * 512 + 128 + j];
}

// ---------- K1: fused STFT-energy + octave-band reduction ----------
// grid (NTILES, NBATCH, 2)  block 192. z=0: target->xbuf, z=1: pred->ybuf
template <int NBINS>
__global__ __launch_bounds__(192) void k_stft(
    const float* __restrict__ targ, const float* __restrict__ pred,
    const float* __restrict__ fmatT, const int* __restrict__ hdr,
    float* __restrict__ xbuf, float* __restrict__ ybuf, int NB) {
    const int F = hdr[0];
    if (NBINS == 1) { if (F > 192) return; } else { if (F <= 192) return; }
    const int tile = blockIdx.x, b = blockIdx.y, z = blockIdx.z;
    const float* __restrict__ sig = z ? pred : targ;
    float* __restrict__ out = z ? ybuf : xbuf;
    __shared__ float sfr[TILE_T * HOP + 128];   // 2176 floats
    __shared__ float wbuf[8 * 514];             // K-chunk weights; later reused as ebuf[16][257]
    const int tid = threadIdx.x;
    const int t0 = tile * TILE_T;

    // frames span -> LDS (coalesced)
    for (int i = tid; i < TILE_T * HOP + 128; i += 192) {
        int g = t0 * HOP + i;
        sfr[i] = (g < SIG_L) ? sig[(long)b * SIG_L + g] : 0.0f;
    }

    float aR[NBINS][TILE_T], aI[NBINS][TILE_T];
#pragma unroll
    for (int n = 0; n < NBINS; ++n)
#pragma unroll
        for (int t = 0; t < TILE_T; ++t) { aR[n][t] = 0.0f; aI[n][t] = 0.0f; }

    const int F2 = 2 * F;
    for (int jc = 0; jc < 32; ++jc) {          // 256 K-cols in chunks of 8
        __syncthreads();
        // stage weights: rows [0,F) re and [257,257+F) im, 8 cols
        for (int jj = 0; jj < 8; ++jj) {
            const float* __restrict__ src = &fmatT[(jc * 8 + jj) * 514];
            for (int rr = tid; rr < F2; rr += 192) {
                int r = (rr < F) ? rr : (rr - F + 257);
                wbuf[jj * F2 + rr] = src[r];
            }
        }
        __syncthreads();
#pragma unroll
        for (int jj4 = 0; jj4 < 2; ++jj4) {
            const int jb = jj4 * 4;
            float wr[NBINS][4], wi[NBINS][4];
#pragma unroll
            for (int n = 0; n < NBINS; ++n) {
                int f = tid + n * 192;
                bool act = f < F;
#pragma unroll
                for (int d = 0; d < 4; ++d) {
                    wr[n][d] = act ? wbuf[(jb + d) * F2 + f] : 0.0f;
                    wi[n][d] = act ? wbuf[(jb + d) * F2 + F + f] : 0.0f;
                }
            }
            const int sb = jc * 8 + jb;
#pragma unroll
            for (int t = 0; t < TILE_T; ++t) {
                float4 s = *(const float4*)&sfr[t * HOP + sb];  // wave-uniform broadcast
#pragma unroll
                for (int n = 0; n < NBINS; ++n) {
                    aR[n][t] += wr[n][0] * s.x; aR[n][t] += wr[n][1] * s.y;
                    aR[n][t] += wr[n][2] * s.z; aR[n][t] += wr[n][3] * s.w;
                    aI[n][t] += wi[n][0] * s.x; aI[n][t] += wi[n][1] * s.y;
                    aI[n][t] += wi[n][2] * s.z; aI[n][t] += wi[n][3] * s.w;
                }
            }
        }
    }
    __syncthreads();
    float* __restrict__ ebuf = wbuf;           // [16][257]
#pragma unroll
    for (int n = 0; n < NBINS; ++n) {
        int f = tid + n * 192;
        if (f < F) {
#pragma unroll
            for (int t = 0; t < TILE_T; ++t)
                ebuf[t * 257 + f] = aR[n][t] * aR[n][t] + aI[n][t] * aI[n][t];
        }
    }
    __syncthreads();
    // band sums -> sqrt -> global
    for (int idx = tid; idx < NB * TILE_T; idx += 192) {
        int k = idx >> 4, t = idx & 15;
        int tg = t0 + t;
        if (tg < NUMF) {
            int fs = hdr[1 + k], fe = hdr[17 + k];
            float s = 0.0f;
            for (int f = fs; f < fe; ++f) s += ebuf[t * 257 + f];
            out[((long)b * NB + k) * NUMF + tg] = sqrtf(s);
        }
    }
}

// ---------- K2: sliding-window correlations, one block per (k,b) ----------
__global__ __launch_bounds__(256) void k_corr(const float* __restrict__ xbuf,
                                              const float* __restrict__ ybuf,
                                              int NB, double* __restrict__ partials) {
    const int k = blockIdx.x, b = blockIdx.y;
    const long roff = ((long)b * NB + k) * NUMF;
    __shared__ float xl[NUMF], yl[NUMF];
    __shared__ double red[256];
    const int tid = threadIdx.x;
    for (int i = tid; i < NUMF; i += 256) { xl[i] = xbuf[roff + i]; yl[i] = ybuf[roff + i]; }
    __syncthreads();
    double loc = 0.0;
    for (int w = tid; w < NWIN; w += 256) {
        float sx = 0, sxx = 0, syy = 0;
        for (int i = 0; i < NFRM; ++i) {
            float xv = xl[w + i], yv = yl[w + i];
            sx += xv; sxx += xv * xv; syy += yv * yv;
        }
        float alpha = sqrtf(sxx / (syy + 1e-7f));
        float sy = 0;
        for (int i = 0; i < NFRM; ++i)
            sy += fminf(alpha * yl[w + i], BETA_F * xl[w + i]);
        float mx = sx * (1.0f / NFRM), my = sy * (1.0f / NFRM);
        float cxx = 0, cyy = 0, cxy = 0;
        for (int i = 0; i < NFRM; ++i) {
            float dx = xl[w + i] - mx;
            float dy = fminf(alpha * yl[w + i], BETA_F * xl[w + i]) - my;
            cxx += dx * dx; cyy += dy * dy; cxy += dx * dy;
        }
        loc += (double)cxy / sqrt((double)cxx * (double)cyy);
    }
    red[tid] = loc;
    __syncthreads();
    for (int s = 128; s > 0; s >>= 1) {
        if (tid < s) red[tid] += red[tid + s];
        __syncthreads();
    }
    if (tid == 0) partials[b * NB + k] = red[0];
}

// ---------- K3: final deterministic reduction ----------
__global__ void k_final(const double* __restrict__ partials, int NB, float* __restrict__ out) {
    __shared__ double red[256];
    const int tid = threadIdx.x;
    const int n = NBATCH * NB;
    double s = 0.0;
    for (int i = tid; i < n; i += 256) s += partials[i];
    red[tid] = s;
    __syncthreads();
    for (int st = 128; st > 0; st >>= 1) {
        if (tid < st) red[tid] += red[tid + st];
        __syncthreads();
    }
    if (tid == 0) out[0] = (float)(-red[0] / ((double)NBATCH * NB * NWIN));
}

extern "C" void kernel_launch(void* const* d_in, const int* in_sizes, int n_in,
                              void* d_out, int out_size, void* d_ws, size_t ws_size,
                              hipStream_t stream) {
    const float* pred   = (const float*)d_in[0];
    const float* targ   = (const float*)d_in[1];
    const float* fftmat = (const float*)d_in[3];
    const float* oct    = (const float*)d_in[4];
    const int NB = in_sizes[4] / NROWS;   // 15

    char* ws = (char*)d_ws;
    int*    hdr      = (int*)ws;                                // 64 ints
    float*  fmatT    = (float*)(ws + 256);                      // 256*514 floats
    size_t  o1       = 256 + (size_t)514 * 256 * 4;
    size_t  xsz      = (size_t)NBATCH * NB * NUMF * 4;
    float*  xbuf     = (float*)(ws + o1);
    float*  ybuf     = (float*)(ws + o1 + xsz);
    double* partials = (double*)(ws + o1 + 2 * xsz);

    hipLaunchKernelGGL(k_scan, dim3(1), dim3(256), 0, stream, oct, NB, hdr);
    hipLaunchKernelGGL(k_tr, dim3(514), dim3(256), 0, stream, fftmat, fmatT);
    dim3 g(NTILES, NBATCH, 2);
    hipLaunchKernelGGL((k_stft<1>), g, dim3(192), 0, stream, targ, pred, fmatT, hdr, xbuf, ybuf, NB);
    hipLaunchKernelGGL((k_stft<2>), g, dim3(192), 0, stream, targ, pred, fmatT, hdr, xbuf, ybuf, NB);
    hipLaunchKernelGGL(k_corr, dim3(NB, NBATCH), dim3(256), 0, stream, xbuf, ybuf, NB, partials);
    hipLaunchKernelGGL(k_final, dim3(1), dim3(256), 0, stream, partials, NB, (float*)d_out);
}

// Round 2
// 940.827 us; speedup vs baseline: 1.2127x; 1.2127x over previous
//
#include <hip/hip_runtime.h>
#include <math.h>

#define SIG_L 128000
#define NBATCH 64
#define NROWS 257
#define HOP 128
#define NUMF 999
#define NFRM 30
#define NWIN 969
#define FT 64            // frames per block (= lanes per wave)
#define NT 16            // ceil(999/64)
#define FB 144           // padded bin count (>= runtime F=138)
#define BETA_F 6.623413251903491f  // 1 + 10^(15/20)

// ---------- K0: octmat scan -> hdr[0]=F, hdr[32+f]=band id (or -1) ----------
__global__ void k_scan(const float* __restrict__ oct, int NB, int* __restrict__ hdr) {
    __shared__ int smin[16], smax[16];
    int tid = threadIdx.x;
    if (tid < NB) { smin[tid] = 0x7fffffff; smax[tid] = -1; }
    __syncthreads();
    for (int idx = tid; idx < NB * NROWS; idx += blockDim.x) {
        int k = idx / NROWS, f = idx % NROWS;
        if (oct[idx] != 0.0f) { atomicMin(&smin[k], f); atomicMax(&smax[k], f); }
    }
    __syncthreads();
    if (tid == 0) {
        int fm = 1;
        for (int k = 0; k < NB; ++k) fm = max(fm, smax[k] + 1);
        hdr[0] = fm;
    }
    if (tid < FB) {
        int kid = -1;
        for (int k = 0; k < NB; ++k)
            if (smax[k] >= 0 && tid >= smin[k] && tid <= smax[k]) kid = k;
        hdr[32 + tid] = kid;
    }
}

// ---------- K0b: weight pack: wmat[f][j4][8] = {re[4j..4j+3], im[4j..4j+3]} ----------
__global__ void k_prep(const float* __restrict__ fftmat, float* __restrict__ wmat) {
    int f = blockIdx.x;            // 0..143
    for (int idx = threadIdx.x; idx < 512; idx += 256) {
        int j4 = idx >> 3, c = idx & 7;
        int col = 128 + j4 * 4 + (c & 3);
        int row = (c < 4) ? f : (257 + f);
        wmat[f * 512 + idx] = fftmat[row * 512 + col];
    }
}

// ---------- K1: STFT energies + band reduce. lane=frame, 18 bins/thread ----------
// grid (NT, NBATCH, 2), block 256 (4 waves). z=0: target->xbuf, z=1: pred->ybuf
__global__ __launch_bounds__(256) void k_stft(
    const float* __restrict__ targ, const float* __restrict__ pred,
    const float* __restrict__ wmat, const int* __restrict__ hdr,
    float* __restrict__ xbuf, float* __restrict__ ybuf, int NB) {
    __shared__ float sfr[32 * 256];     // K-half: 32 j-quads x 64 frames x 4 (conflict-free b128)
    __shared__ float bacc[16 * FT];     // band accumulators [k][t]
    const int tid = threadIdx.x;
    const int lane = tid & 63;
    const int wid = __builtin_amdgcn_readfirstlane(tid >> 6);
    const int tile = blockIdx.x, b = blockIdx.y, z = blockIdx.z;
    const float* __restrict__ sig = z ? pred : targ;
    float* __restrict__ out = z ? ybuf : xbuf;
    const int t0 = tile * FT;
    const long boff = (long)b * SIG_L;

    for (int i = tid; i < 16 * FT; i += 256) bacc[i] = 0.0f;

    for (int pass = 0; pass < 2; ++pass) {
        const int wb = pass * 72 + wid * 18;   // wave's bin base (uniform)
        float aR[18], aI[18];
#pragma unroll
        for (int ff = 0; ff < 18; ++ff) { aR[ff] = 0.0f; aI[ff] = 0.0f; }

        for (int h = 0; h < 2; ++h) {          // K halves: j in [h*128, h*128+128)
            __syncthreads();
#pragma unroll
            for (int it = 0; it < 32; ++it) {  // stage: sfr[j4*256 + t*4 + c]
                int idx = it * 256 + tid;
                int c = idx & 3, t = (idx >> 2) & 63, j4 = idx >> 8;
                int g = (t0 + t) * HOP + h * 128 + j4 * 4 + c;
                sfr[idx] = (g < SIG_L) ? sig[boff + g] : 0.0f;
            }
            __syncthreads();
#pragma unroll 2
            for (int j4 = 0; j4 < 32; ++j4) {
                const float4 s = *(const float4*)&sfr[j4 * 256 + lane * 4];
                const int j4g = h * 32 + j4;
#pragma unroll
                for (int ff = 0; ff < 18; ++ff) {
                    const float* wp = &wmat[(size_t)(wb + ff) * 512 + j4g * 8]; // uniform -> s_load
                    float r = aR[ff], q = aI[ff];
                    r = fmaf(wp[0], s.x, r); r = fmaf(wp[1], s.y, r);
                    r = fmaf(wp[2], s.z, r); r = fmaf(wp[3], s.w, r);
                    q = fmaf(wp[4], s.x, q); q = fmaf(wp[5], s.y, q);
                    q = fmaf(wp[6], s.z, q); q = fmaf(wp[7], s.w, q);
                    aR[ff] = r; aI[ff] = q;
                }
            }
        }
        // energies -> band accumulate (kid wave-uniform; lanes hit distinct addrs)
#pragma unroll
        for (int ff = 0; ff < 18; ++ff) {
            int kid = hdr[32 + wb + ff];
            if (kid >= 0) {
                float e = aR[ff] * aR[ff] + aI[ff] * aI[ff];
                atomicAdd(&bacc[kid * FT + lane], e);
            }
        }
    }
    __syncthreads();
    for (int idx = tid; idx < NB * FT; idx += 256) {
        int k = idx >> 6, t = idx & 63;
        int tg = t0 + t;
        if (tg < NUMF)
            out[((long)b * NB + k) * NUMF + tg] = sqrtf(bacc[k * FT + t]);
    }
}

// ---------- K2: sliding-window correlations, one block per (k,b) ----------
__global__ __launch_bounds__(256) void k_corr(const float* __restrict__ xbuf,
                                              const float* __restrict__ ybuf,
                                              int NB, double* __restrict__ partials) {
    const int k = blockIdx.x, b = blockIdx.y;
    const long roff = ((long)b * NB + k) * NUMF;
    __shared__ float xl[NUMF], yl[NUMF];
    __shared__ double red[256];
    const int tid = threadIdx.x;
    for (int i = tid; i < NUMF; i += 256) { xl[i] = xbuf[roff + i]; yl[i] = ybuf[roff + i]; }
    __syncthreads();
    double loc = 0.0;
    for (int w = tid; w < NWIN; w += 256) {
        float sx = 0, sxx = 0, syy = 0;
        for (int i = 0; i < NFRM; ++i) {
            float xv = xl[w + i], yv = yl[w + i];
            sx += xv; sxx += xv * xv; syy += yv * yv;
        }
        float alpha = sqrtf(sxx / (syy + 1e-7f));
        float sy = 0;
        for (int i = 0; i < NFRM; ++i)
            sy += fminf(alpha * yl[w + i], BETA_F * xl[w + i]);
        float mx = sx * (1.0f / NFRM), my = sy * (1.0f / NFRM);
        float cxx = 0, cyy = 0, cxy = 0;
        for (int i = 0; i < NFRM; ++i) {
            float dx = xl[w + i] - mx;
            float dy = fminf(alpha * yl[w + i], BETA_F * xl[w + i]) - my;
            cxx += dx * dx; cyy += dy * dy; cxy += dx * dy;
        }
        loc += (double)cxy / sqrt((double)cxx * (double)cyy);
    }
    red[tid] = loc;
    __syncthreads();
    for (int s = 128; s > 0; s >>= 1) {
        if (tid < s) red[tid] += red[tid + s];
        __syncthreads();
    }
    if (tid == 0) partials[b * NB + k] = red[0];
}

// ---------- K3: final deterministic reduction ----------
__global__ void k_final(const double* __restrict__ partials, int NB, float* __restrict__ out) {
    __shared__ double red[256];
    const int tid = threadIdx.x;
    const int n = NBATCH * NB;
    double s = 0.0;
    for (int i = tid; i < n; i += 256) s += partials[i];
    red[tid] = s;
    __syncthreads();
    for (int st = 128; st > 0; st >>= 1) {
        if (tid < st) red[tid] += red[tid + st];
        __syncthreads();
    }
    if (tid == 0) out[0] = (float)(-red[0] / ((double)NBATCH * NB * NWIN));
}

extern "C" void kernel_launch(void* const* d_in, const int* in_sizes, int n_in,
                              void* d_out, int out_size, void* d_ws, size_t ws_size,
                              hipStream_t stream) {
    const float* pred   = (const float*)d_in[0];
    const float* targ   = (const float*)d_in[1];
    const float* fftmat = (const float*)d_in[3];
    const float* oct    = (const float*)d_in[4];
    const int NB = in_sizes[4] / NROWS;   // 15

    char* ws = (char*)d_ws;
    int*    hdr      = (int*)ws;                       // 1 KB
    float*  wmat     = (float*)(ws + 1024);            // 144*512*4 = 294912 B
    size_t  o1       = 1024 + (size_t)FB * 512 * 4;
    size_t  xsz      = (size_t)NBATCH * 15 * NUMF * 4; // sized for NB<=15
    float*  xbuf     = (float*)(ws + o1);
    float*  ybuf     = (float*)(ws + o1 + xsz);
    double* partials = (double*)(ws + o1 + 2 * xsz);

    hipLaunchKernelGGL(k_scan, dim3(1), dim3(256), 0, stream, oct, NB, hdr);
    hipLaunchKernelGGL(k_prep, dim3(FB), dim3(256), 0, stream, fftmat, wmat);
    hipLaunchKernelGGL(k_stft, dim3(NT, NBATCH, 2), dim3(256), 0, stream,
                       targ, pred, wmat, hdr, xbuf, ybuf, NB);
    hipLaunchKernelGGL(k_corr, dim3(NB, NBATCH), dim3(256), 0, stream, xbuf, ybuf, NB, partials);
    hipLaunchKernelGGL(k_final, dim3(1), dim3(256), 0, stream, partials, NB, (float*)d_out);
}

// Round 3
// 231.615 us; speedup vs baseline: 4.9260x; 4.0620x over previous
//
#include <hip/hip_runtime.h>
#include <math.h>

#define SIG_L 128000
#define NBATCH 64
#define NROWS 257
#define HOP 128
#define NUMF 999
#define NFRM 30
#define NWIN 969
#define NB_MAX 16
#define FBINS 160          // padded bin count (runtime F = 138)
#define BETA_F 6.623413251903491f  // 1 + 10^(15/20)

typedef __attribute__((ext_vector_type(8))) short short8;
typedef __attribute__((ext_vector_type(16))) float f32x16;
typedef unsigned short ushort_t;

// RNE split of fp32 into bf16 hi + bf16 lo (hi RNE; rem = v - hi exact in fp32)
__device__ inline ushort_t bf_hi_rne(float v, float* rem) {
    unsigned u = __float_as_uint(v);
    unsigned hr = (u + 0x7FFFu + ((u >> 16) & 1u)) & 0xFFFF0000u;
    *rem = v - __uint_as_float(hr);
    return (ushort_t)(hr >> 16);
}
__device__ inline ushort_t bf_rne(float v) {
    unsigned u = __float_as_uint(v);
    return (ushort_t)((u + 0x7FFFu + ((u >> 16) & 1u)) >> 16);
}

// ---------- K0: octmat scan -> hdr[32+f] = band id of bin f (or -1) ----------
__global__ void k_scan(const float* __restrict__ oct, int NB, int* __restrict__ hdr) {
    __shared__ int smin[16], smax[16];
    int tid = threadIdx.x;
    if (tid < NB) { smin[tid] = 0x7fffffff; smax[tid] = -1; }
    __syncthreads();
    for (int idx = tid; idx < NB * NROWS; idx += blockDim.x) {
        int k = idx / NROWS, f = idx % NROWS;
        if (oct[idx] != 0.0f) { atomicMin(&smin[k], f); atomicMax(&smax[k], f); }
    }
    __syncthreads();
    if (tid < FBINS) {
        int kid = -1;
        for (int k = 0; k < NB; ++k)
            if (smax[k] >= 0 && tid >= smin[k] && tid <= smax[k]) kid = k;
        hdr[32 + tid] = kid;
    }
}

// ---------- K0b: split weights to bf16 hi/lo, packed rows ----------
// row = q*64 + h*32 + s  ->  (h ? im : re) of bin q*32+s ; col k -> fftmat col 128+k
__global__ void k_prep(const float* __restrict__ fftmat,
                       ushort_t* __restrict__ wh, ushort_t* __restrict__ wl) {
    int row = blockIdx.x;          // 0..319
    int col = threadIdx.x;         // 0..255
    int q = row >> 6, rem = row & 63, h = rem >> 5, s = rem & 31;
    int bin = q * 32 + s;          // 0..159 (< 257, always a valid fft row)
    int srow = h ? (NROWS + bin) : bin;
    float v = fftmat[srow * 512 + 128 + col];
    float lo;
    ushort_t hb = bf_hi_rne(v, &lo);
    wh[row * 256 + col] = hb;
    wl[row * 256 + col] = bf_rne(lo);
}

// ---------- K1: MFMA STFT energies + band reduce ----------
// grid (8, NBATCH, 2), block 256 (4 waves x 32 frames). z=0: targ->xbuf, z=1: pred->ybuf
// Stores band ENERGIES (sqrt deferred to k_corr).
__global__ __launch_bounds__(256, 2) void k_stft(
    const float* __restrict__ targ, const float* __restrict__ pred,
    const ushort_t* __restrict__ wh, const ushort_t* __restrict__ wl,
    const int* __restrict__ hdr,
    float* __restrict__ xbuf, float* __restrict__ ybuf, int NB) {
    __shared__ float bacc[NB_MAX * 128];
    __shared__ int kmap[FBINS];
    const int tid = threadIdx.x;
    const int lane = tid & 63;
    const int wv = __builtin_amdgcn_readfirstlane(tid >> 6);
    const int jloc = lane & 31, kh = lane >> 5;
    const int b = blockIdx.y, z = blockIdx.z;
    const int t0 = blockIdx.x * 128;
    const float* __restrict__ sig = z ? pred : targ;
    float* __restrict__ out = z ? ybuf : xbuf;

    for (int i = tid; i < NB_MAX * 128; i += 256) bacc[i] = 0.0f;
    for (int i = tid; i < FBINS; i += 256) kmap[i] = hdr[32 + i];
    __syncthreads();

    const int frame = t0 + wv * 32 + jloc;      // this lane's frame (B column)
    const bool fval = frame < NUMF;             // valid frames never read OOB samples
    const float* sp = sig + (size_t)b * SIG_L + (size_t)frame * HOP;

    f32x16 acc[10];
#pragma unroll
    for (int m = 0; m < 10; ++m)
#pragma unroll
        for (int e = 0; e < 16; ++e) acc[m][e] = 0.0f;

    const size_t abase = (size_t)jloc * 256 + (size_t)kh * 8;

#pragma unroll 1
    for (int kk = 0; kk < 16; ++kk) {
        // B fragment: 8 consecutive samples (k = kk*16 + kh*8 + e), split to bf16 hi/lo
        float s8[8];
        if (fval) {
            float4 f0 = *(const float4*)(sp + kk * 16 + kh * 8);
            float4 f1 = *(const float4*)(sp + kk * 16 + kh * 8 + 4);
            s8[0] = f0.x; s8[1] = f0.y; s8[2] = f0.z; s8[3] = f0.w;
            s8[4] = f1.x; s8[5] = f1.y; s8[6] = f1.z; s8[7] = f1.w;
        } else {
#pragma unroll
            for (int e = 0; e < 8; ++e) s8[e] = 0.0f;
        }
        short8 Sh, Sl;
#pragma unroll
        for (int e = 0; e < 8; ++e) {
            float rem;
            Sh[e] = (short)bf_hi_rne(s8[e], &rem);
            Sl[e] = (short)bf_rne(rem);
        }
        const size_t koff = abase + (size_t)kk * 16;
#pragma unroll
        for (int bt = 0; bt < 2; ++bt) {
            short8 Ah[5], Al[5];
#pragma unroll
            for (int i = 0; i < 5; ++i) {
                const int mt = bt * 5 + i;
                Ah[i] = *(const short8*)(wh + (size_t)mt * 8192 + koff);
                Al[i] = *(const short8*)(wl + (size_t)mt * 8192 + koff);
            }
#pragma unroll
            for (int i = 0; i < 5; ++i) {
                const int mt = bt * 5 + i;
                acc[mt] = __builtin_amdgcn_mfma_f32_32x32x16_bf16(Ah[i], Sh, acc[mt], 0, 0, 0);
                acc[mt] = __builtin_amdgcn_mfma_f32_32x32x16_bf16(Ah[i], Sl, acc[mt], 0, 0, 0);
                acc[mt] = __builtin_amdgcn_mfma_f32_32x32x16_bf16(Al[i], Sh, acc[mt], 0, 0, 0);
            }
        }
    }

    // epilogue: e = re^2 + im^2, run-compressed band accumulate into LDS
    const int fl = wv * 32 + jloc;              // block-local frame 0..127
#pragma unroll
    for (int q = 0; q < 5; ++q) {
        float run = 0.0f; int runk = -1;
#pragma unroll
        for (int r = 0; r < 16; ++r) {
            const int row = (r & 3) + 8 * (r >> 2) + 4 * kh;   // C/D row map (m74/m101)
            const int kid = kmap[q * 32 + row];
            const float vr = acc[2 * q][r], vi = acc[2 * q + 1][r];
            const float e = vr * vr + vi * vi;
            if (kid != runk) {
                if (runk >= 0) atomicAdd(&bacc[runk * 128 + fl], run);
                run = 0.0f; runk = kid;
            }
            if (kid >= 0) run += e;
        }
        if (runk >= 0) atomicAdd(&bacc[runk * 128 + fl], run);
    }
    __syncthreads();
    for (int idx = tid; idx < NB * 128; idx += 256) {
        int k = idx >> 7, t = idx & 127;
        int tg = t0 + t;
        if (tg < NUMF)
            out[((size_t)b * NB + k) * NUMF + tg] = bacc[k * 128 + t];
    }
}

// ---------- K2: sliding-window correlations (reads energies, applies sqrt) ----------
__global__ __launch_bounds__(256) void k_corr(const float* __restrict__ xbuf,
                                              const float* __restrict__ ybuf,
                                              int NB, double* __restrict__ partials) {
    const int k = blockIdx.x, b = blockIdx.y;
    const long roff = ((long)b * NB + k) * NUMF;
    __shared__ float xl[NUMF], yl[NUMF];
    __shared__ double red[256];
    const int tid = threadIdx.x;
    for (int i = tid; i < NUMF; i += 256) {
        xl[i] = sqrtf(xbuf[roff + i]);
        yl[i] = sqrtf(ybuf[roff + i]);
    }
    __syncthreads();
    double loc = 0.0;
    for (int w = tid; w < NWIN; w += 256) {
        float sx = 0, sxx = 0, syy = 0;
        for (int i = 0; i < NFRM; ++i) {
            float xv = xl[w + i], yv = yl[w + i];
            sx += xv; sxx += xv * xv; syy += yv * yv;
        }
        float alpha = sqrtf(sxx / (syy + 1e-7f));
        float sy = 0;
        for (int i = 0; i < NFRM; ++i)
            sy += fminf(alpha * yl[w + i], BETA_F * xl[w + i]);
        float mx = sx * (1.0f / NFRM), my = sy * (1.0f / NFRM);
        float cxx = 0, cyy = 0, cxy = 0;
        for (int i = 0; i < NFRM; ++i) {
            float dx = xl[w + i] - mx;
            float dy = fminf(alpha * yl[w + i], BETA_F * xl[w + i]) - my;
            cxx += dx * dx; cyy += dy * dy; cxy += dx * dy;
        }
        loc += (double)cxy / sqrt((double)cxx * (double)cyy);
    }
    red[tid] = loc;
    __syncthreads();
    for (int s = 128; s > 0; s >>= 1) {
        if (tid < s) red[tid] += red[tid + s];
        __syncthreads();
    }
    if (tid == 0) partials[b * NB + k] = red[0];
}

// ---------- K3: final deterministic reduction ----------
__global__ void k_final(const double* __restrict__ partials, int NB, float* __restrict__ out) {
    __shared__ double red[256];
    const int tid = threadIdx.x;
    const int n = NBATCH * NB;
    double s = 0.0;
    for (int i = tid; i < n; i += 256) s += partials[i];
    red[tid] = s;
    __syncthreads();
    for (int st = 128; st > 0; st >>= 1) {
        if (tid < st) red[tid] += red[tid + st];
        __syncthreads();
    }
    if (tid == 0) out[0] = (float)(-red[0] / ((double)NBATCH * NB * NWIN));
}

extern "C" void kernel_launch(void* const* d_in, const int* in_sizes, int n_in,
                              void* d_out, int out_size, void* d_ws, size_t ws_size,
                              hipStream_t stream) {
    const float* pred   = (const float*)d_in[0];
    const float* targ   = (const float*)d_in[1];
    const float* fftmat = (const float*)d_in[3];
    const float* oct    = (const float*)d_in[4];
    const int NB = in_sizes[4] / NROWS;   // 15

    char* ws = (char*)d_ws;
    int*      hdr = (int*)ws;                              // 1 KB
    ushort_t* wh  = (ushort_t*)(ws + 1024);                // 320*256*2 = 163840 B
    ushort_t* wl  = (ushort_t*)(ws + 1024 + 163840);
    size_t o1 = 1024 + 2 * 163840;
    size_t xsz = (size_t)NBATCH * NB_MAX * NUMF * 4;
    float*  xbuf = (float*)(ws + o1);
    float*  ybuf = (float*)(ws + o1 + xsz);
    double* partials = (double*)(ws + o1 + 2 * xsz);

    hipLaunchKernelGGL(k_scan, dim3(1), dim3(256), 0, stream, oct, NB, hdr);
    hipLaunchKernelGGL(k_prep, dim3(320), dim3(256), 0, stream, fftmat, wh, wl);
    hipLaunchKernelGGL(k_stft, dim3(8, NBATCH, 2), dim3(256), 0, stream,
                       targ, pred, wh, wl, hdr, xbuf, ybuf, NB);
    hipLaunchKernelGGL(k_corr, dim3(NB, NBATCH), dim3(256), 0, stream, xbuf, ybuf, NB, partials);
    hipLaunchKernelGGL(k_final, dim3(1), dim3(256), 0, stream, partials, NB, (float*)d_out);
}